// Round 4
// baseline (516.382 us; speedup 1.0000x reference)
//
#include <hip/hip_runtime.h>

// B=4,H=16,S=1024,D=64. Outputs: out [64,1024,64] fp32 then attn [64,1024,1024] fp32.
// Flat softmax (scores bounded -> exp can't overflow), e kept in bf16 regs (xsb, 64 VGPR).
// Loop1: QK^T per 64-key tile -> e, lane-local sums. Loop2: sP/sV staging, PV MFMA on
// unnormalized e, attn written from sP readback as full-128B-line NT stores (overlapped
// with MFMA). 32 KB LDS (K region aliased by sP+sums in loop2) + VGPR<=128 -> 4 blocks/CU.
constexpr int SEQ = 1024;
constexpr int DH  = 64;
constexpr int QR  = 32;        // q rows per block
constexpr int KT  = 64;        // key tile
constexpr int NKT = SEQ / KT;  // 16

// LDS layout (bytes). All tiles use 128 B rows with XOR swizzle (row&7)<<4.
constexpr int SK0 = 0;         // loop1: K buf0 [64 keys][64 d] bf16 (8 KB)
constexpr int SK1 = 8192;      // loop1: K buf1 (8 KB)
constexpr int SP0 = 0;         // loop2: P buf0 [32 q][64 keys] bf16 (4 KB)  (aliases SK0)
constexpr int SP1 = 4096;      // loop2: P buf1 (4 KB)                       (aliases SK0)
constexpr int SRL = 8192;      // loop2: float[2][32] row sums (256 B)       (aliases SK1)
constexpr int SV0 = 16384;     // V^T buf0 [64 d][64 keys] bf16 (8 KB)
constexpr int SV1 = 24576;     // V^T buf1 (8 KB)
constexpr int SMEM_BYTES = 32768;   // 32 KB -> LDS allows 5 blocks/CU; VGPR caps at 4

typedef __bf16 bf16x8 __attribute__((ext_vector_type(8)));
typedef __bf16 bf16x4 __attribute__((ext_vector_type(4)));
typedef float  f32x4  __attribute__((ext_vector_type(4)));

__device__ __forceinline__ char* ldsa(char* s, int base, int row, int colB) {
    return s + base + row * 128 + (colB ^ ((row & 7) << 4));
}

__global__ __launch_bounds__(256, 4)
void attn_flash_kernel(const float* __restrict__ Q, const float* __restrict__ K,
                       const float* __restrict__ V, const float* __restrict__ bias,
                       float* __restrict__ out, float* __restrict__ attn)
{
    __shared__ __align__(16) char smem[SMEM_BYTES];

    const int tid = threadIdx.x;
    const int l   = tid & 63;
    const int w   = tid >> 6;
    const int qt  = w & 1;             // q subtile (16 rows)
    const int ch  = w >> 1;            // key half (32 of 64) in QK; d half in PV
    const int lm  = l & 15;
    const int lq  = l >> 4;
    // qb-major: head = blk & 63 -> head h pinned to XCD h%8; K/V stay L2-resident per XCD.
    const int head = blockIdx.x & 63;
    const int q0   = (blockIdx.x >> 6) * QR;
    const float scale = 0.125f;

    const float* Qh = Q + (size_t)head * SEQ * DH;
    const float* Kh = K + (size_t)head * SEQ * DH;
    const float* Vh = V + (size_t)head * SEQ * DH;
    float* outh  = out  + (size_t)head * SEQ * DH;
    float* attnh = attn + (size_t)head * SEQ * SEQ;

    const int srow = tid >> 4;         // K staging row (16 rows per 256-thread step)
    const int sdg  = tid & 15;         // staging 4-float group
    const int vkb  = tid >> 4;         // V staging: key group of 4 (coalesced inner d)
    const int vdb  = tid & 15;         // V staging: d group of 4
    const int rowg_l = qt * 16 + lq * 4;   // tile-local first of 4 q rows (C-layout)

    // ---- prologue: issue K tile-0 loads; Q fragments straight from global ----
    f32x4 kv[4];
    #pragma unroll
    for (int i = 0; i < 4; ++i)
        kv[i] = *(const f32x4*)(Kh + (size_t)(srow + 16 * i) * DH + sdg * 4);

    bf16x8 aQ[2];
    {
        const float* qrow = Qh + (size_t)(q0 + qt * 16 + lm) * DH;
        #pragma unroll
        for (int ks = 0; ks < 2; ++ks) {
            f32x4 a = *(const f32x4*)(qrow + ks * 32 + lq * 8);
            f32x4 b = *(const f32x4*)(qrow + ks * 32 + lq * 8 + 4);
            bf16x8 f;
            f[0] = (__bf16)a[0]; f[1] = (__bf16)a[1]; f[2] = (__bf16)a[2]; f[3] = (__bf16)a[3];
            f[4] = (__bf16)b[0]; f[5] = (__bf16)b[1]; f[6] = (__bf16)b[2]; f[7] = (__bf16)b[3];
            aQ[ks] = f;
        }
    }

    // =================== Loop 1: QK^T + bias -> e (bf16 regs), lane-local sums ===================
    bf16x4 xsb[NKT][2];                // 64 VGPR: e values for this thread
    float ssum[4] = {0.f, 0.f, 0.f, 0.f};

    #pragma unroll
    for (int kt = 0; kt < NKT; ++kt) {
        const int bufK = (kt & 1) ? SK1 : SK0;
        // write staged K regs -> LDS (vmcnt wait lands here)
        #pragma unroll
        for (int i = 0; i < 4; ++i) {
            bf16x4 b;
            b[0] = (__bf16)kv[i][0]; b[1] = (__bf16)kv[i][1];
            b[2] = (__bf16)kv[i][2]; b[3] = (__bf16)kv[i][3];
            *(bf16x4*)ldsa(smem, bufK, srow + 16 * i, sdg * 8) = b;
        }
        __syncthreads();               // K(kt) visible; K(kt-2) readers done

        // issue next K tile loads (in flight across MFMA + exp)
        if (kt < NKT - 1) {
            #pragma unroll
            for (int i = 0; i < 4; ++i)
                kv[i] = *(const f32x4*)(Kh + (size_t)((kt + 1) * KT + srow + 16 * i) * DH + sdg * 4);
        }
        // bias for this tile (hidden under MFMA)
        const int colg = kt * KT + ch * 32 + lm;
        float bb[4][2];
        #pragma unroll
        for (int r = 0; r < 4; ++r) {
            const float* brow = bias + (size_t)(q0 + rowg_l + r) * SEQ + colg;
            bb[r][0] = brow[0]; bb[r][1] = brow[16];
        }

        f32x4 acc[2] = {{0,0,0,0},{0,0,0,0}};
        __builtin_amdgcn_s_setprio(1);
        #pragma unroll
        for (int ks = 0; ks < 2; ++ks) {
            #pragma unroll
            for (int c = 0; c < 2; ++c) {
                bf16x8 bf = *(const bf16x8*)ldsa(smem, bufK, (ch * 2 + c) * 16 + lm, ks * 64 + lq * 16);
                acc[c] = __builtin_amdgcn_mfma_f32_16x16x32_bf16(aQ[ks], bf, acc[c], 0, 0, 0);
            }
        }
        __builtin_amdgcn_s_setprio(0);

        // e = exp(x*scale + bias): f32 sum, bf16 register carrier
        #pragma unroll
        for (int c = 0; c < 2; ++c) {
            #pragma unroll
            for (int r = 0; r < 4; ++r) {
                float e = __expf(acc[c][r] * scale + bb[r][c]);
                ssum[r] += e;
                xsb[kt][c][r] = (__bf16)e;
            }
        }
    }

    // ---- mid: V tile-0 prefetch, row-sum reduce, linv ----
    f32x4 vv[4];
    #pragma unroll
    for (int j = 0; j < 4; ++j)
        vv[j] = *(const f32x4*)(Vh + (size_t)(vkb * 4 + j) * DH + vdb * 4);

    #pragma unroll
    for (int r = 0; r < 4; ++r) {
        float s = ssum[r];
        #pragma unroll
        for (int off = 1; off < 16; off <<= 1)
            s += __shfl_xor(s, off);
        ssum[r] = s;
    }
    __syncthreads();                   // all QK reads done -> SK1 region reusable as sRL
    float* sRLp = (float*)(smem + SRL);
    if (lm == 0) {
        #pragma unroll
        for (int r = 0; r < 4; ++r)
            sRLp[ch * 32 + rowg_l + r] = ssum[r];
    }
    __syncthreads();                   // sRL visible
    float linv[4];
    #pragma unroll
    for (int r = 0; r < 4; ++r)
        linv[r] = 1.0f / (sRLp[rowg_l + r] + sRLp[32 + rowg_l + r]);
    const int arow = tid >> 3;         // attn-store row for this thread
    const int achk = tid & 7;          // attn-store 4-float chunk
    const float linv_s = 1.0f / (sRLp[arow] + sRLp[32 + arow]);

    // =================== Loop 2: stage sP/sV, attn full-line NT stores, PV ===================
    const int dtb = ch * 2;            // 2 d-subtiles of 16 per wave
    f32x4 oacc[2] = {{0,0,0,0},{0,0,0,0}};

    #pragma unroll
    for (int kt = 0; kt < NKT; ++kt) {
        const int bufP = (kt & 1) ? SP1 : SP0;
        const int bufV = (kt & 1) ? SV1 : SV0;

        // write staged V regs -> sV^T (4x4 micro-transpose)
        #pragma unroll
        for (int jj = 0; jj < 4; ++jj) {
            bf16x4 b;
            b[0] = (__bf16)vv[0][jj]; b[1] = (__bf16)vv[1][jj];
            b[2] = (__bf16)vv[2][jj]; b[3] = (__bf16)vv[3][jj];
            *(bf16x4*)ldsa(smem, bufV, vdb * 4 + jj, vkb * 8) = b;
        }
        // write sP = raw bf16 e (column fragments -> scalar b16 writes, swizzle spreads banks)
        #pragma unroll
        for (int c = 0; c < 2; ++c)
            #pragma unroll
            for (int r = 0; r < 4; ++r)
                *(__bf16*)ldsa(smem, bufP, rowg_l + r, (ch * 32 + c * 16 + lm) * 2) = xsb[kt][c][r];
        __syncthreads();               // sP(kt)+sV(kt) visible; buf readers from kt-2 done

        // issue next V tile (consumed at next iter's top)
        if (kt < NKT - 1) {
            #pragma unroll
            for (int j = 0; j < 4; ++j)
                vv[j] = *(const f32x4*)(Vh + (size_t)((kt + 1) * KT + vkb * 4 + j) * DH + vdb * 4);
        }

        // attn stores: sP readback, x linv, exact 128 B line per wave instruction
        {
            bf16x4 pa = *(const bf16x4*)ldsa(smem, bufP, arow, achk * 8);
            bf16x4 pb = *(const bf16x4*)ldsa(smem, bufP, arow, 64 + achk * 8);
            f32x4 wa, wb;
            #pragma unroll
            for (int i = 0; i < 4; ++i) { wa[i] = (float)pa[i] * linv_s; wb[i] = (float)pb[i] * linv_s; }
            float* ap = attnh + (size_t)(q0 + arow) * SEQ + kt * KT;
            __builtin_nontemporal_store(wa, (f32x4*)(ap + achk * 4));
            __builtin_nontemporal_store(wb, (f32x4*)(ap + 32 + achk * 4));
        }

        // PV on unnormalized e
        __builtin_amdgcn_s_setprio(1);
        #pragma unroll
        for (int ks = 0; ks < 2; ++ks) {
            bf16x8 af = *(const bf16x8*)ldsa(smem, bufP, qt * 16 + lm, ks * 64 + lq * 16);
            #pragma unroll
            for (int c = 0; c < 2; ++c) {
                bf16x8 bf = *(const bf16x8*)ldsa(smem, bufV, (dtb + c) * 16 + lm, ks * 64 + lq * 16);
                oacc[c] = __builtin_amdgcn_mfma_f32_16x16x32_bf16(af, bf, oacc[c], 0, 0, 0);
            }
        }
        __builtin_amdgcn_s_setprio(0);
    }

    // ---- out: scale unnormalized PV accumulator ----
    #pragma unroll
    for (int c = 0; c < 2; ++c)
        #pragma unroll
        for (int r = 0; r < 4; ++r)
            __builtin_nontemporal_store(oacc[c][r] * linv[r],
                outh + (size_t)(q0 + rowg_l + r) * DH + (dtb + c) * 16 + lm);
}

extern "C" void kernel_launch(void* const* d_in, const int* in_sizes, int n_in,
                              void* d_out, int out_size, void* d_ws, size_t ws_size,
                              hipStream_t stream) {
    const float* Q    = (const float*)d_in[0];
    const float* K    = (const float*)d_in[1];
    const float* V    = (const float*)d_in[2];
    const float* bias = (const float*)d_in[3];
    float* out  = (float*)d_out;
    float* attn = (float*)d_out + 4 * 16 * 1024 * 64;
    dim3 grid(64 * (SEQ / QR));
    dim3 block(256);
    attn_flash_kernel<<<grid, block, 0, stream>>>(Q, K, V, bias, out, attn);
}

// Round 5
// 497.679 us; speedup vs baseline: 1.0376x; 1.0376x over previous
//
#include <hip/hip_runtime.h>

// B=4,H=16,S=1024,D=64. Outputs: out [64,1024,64] fp32 then attn [64,1024,1024] fp32.
// Flat softmax (scores bounded -> exp can't overflow); e kept as bf16 regs (xsb).
// Loop1 (8 iters, KT=128): QK^T -> e, lane-local sums. 1 barrier/iter, K double-buffered.
// Loop2 (8 iters): sP/sV^T staging, attn NT stores from sP readback with 512B-contiguous
// per-instruction coverage (full 256B sectors -> no NT write amplification), PV MFMA on
// unnormalized e. LDS 48.3 KB (K region aliased by V^T region) + low VGPR -> 3 blocks/CU.
constexpr int SEQ = 1024;
constexpr int DH  = 64;
constexpr int QR  = 32;        // q rows per block
constexpr int KT  = 128;       // key tile
constexpr int NKT = SEQ / KT;  // 8

// LDS layout (bytes). Region A aliased: loop1 K dbuf / loop2 V^T dbuf.
constexpr int SA0 = 0;         // K buf0 [128 k][64 d] bf16 (kadr) / V^T buf0 [64 d][128 k] (vadr)
constexpr int SA1 = 16384;     // K buf1 / V^T buf1
constexpr int SP0 = 32768;     // sP buf0 [32 q][128 k] bf16 (vadr)
constexpr int SP1 = 40960;     // sP buf1
constexpr int SRL = 49152;     // float[2][32] row sums
constexpr int SMEM_BYTES = 49408;   // 3 blocks/CU by LDS (3x48.25 KB < 160 KB)

typedef __bf16 bf16x8 __attribute__((ext_vector_type(8)));
typedef __bf16 bf16x4 __attribute__((ext_vector_type(4)));
typedef float  f32x4  __attribute__((ext_vector_type(4)));

// 128 B rows, swizzle (row&7)<<4  -- measured 0-conflict for K staging/reads (R3)
__device__ __forceinline__ char* kadr(char* s, int base, int row, int colB) {
    return s + base + row * 128 + (colB ^ ((row & 7) << 4));
}
// 256 B rows, swizzle (row&15)<<4 -- measured 0-conflict for V^T/sP (R3)
__device__ __forceinline__ char* vadr(char* s, int base, int row, int colB) {
    return s + base + row * 256 + (colB ^ ((row & 15) << 4));
}

__global__ __launch_bounds__(256, 3)
void attn_flash_kernel(const float* __restrict__ Q, const float* __restrict__ K,
                       const float* __restrict__ V, const float* __restrict__ bias,
                       float* __restrict__ out, float* __restrict__ attn)
{
    __shared__ __align__(16) char smem[SMEM_BYTES];

    const int tid = threadIdx.x;
    const int l   = tid & 63;
    const int w   = tid >> 6;
    const int qt  = w & 1;             // q subtile (16 rows)
    const int ch  = w >> 1;            // key-column half (64 of 128) in QK; d half in PV
    const int lm  = l & 15;
    const int lq  = l >> 4;
    // qb-major: head = blk & 63 -> head h pinned to XCD h%8; K/V L2-resident per XCD.
    const int head = blockIdx.x & 63;
    const int q0   = (blockIdx.x >> 6) * QR;
    const float scale = 0.125f;

    const float* Qh = Q + (size_t)head * SEQ * DH;
    const float* Kh = K + (size_t)head * SEQ * DH;
    const float* Vh = V + (size_t)head * SEQ * DH;
    float* outh  = out  + (size_t)head * SEQ * DH;
    float* attnh = attn + (size_t)head * SEQ * SEQ;

    const int srow = tid >> 4;         // K staging row base (16 rows per 256-thread step)
    const int sdg  = tid & 15;         // staging 4-float group
    const int vkb  = tid & 31;         // V staging: key group of 4
    const int vdb0 = tid >> 5;         // V staging: d group base
    const int rowg_l = qt * 16 + lq * 4;   // tile-local first of 4 q rows (C-layout)

    // ---- prologue: issue K tile-0 loads; Q fragments straight from global ----
    f32x4 kv[8];
    #pragma unroll
    for (int i = 0; i < 8; ++i)
        kv[i] = *(const f32x4*)(Kh + (size_t)(srow + 16 * i) * DH + sdg * 4);

    bf16x8 aQ[2];
    {
        const float* qrow = Qh + (size_t)(q0 + qt * 16 + lm) * DH;
        #pragma unroll
        for (int ks = 0; ks < 2; ++ks) {
            f32x4 a = *(const f32x4*)(qrow + ks * 32 + lq * 8);
            f32x4 b = *(const f32x4*)(qrow + ks * 32 + lq * 8 + 4);
            bf16x8 f;
            f[0] = (__bf16)a[0]; f[1] = (__bf16)a[1]; f[2] = (__bf16)a[2]; f[3] = (__bf16)a[3];
            f[4] = (__bf16)b[0]; f[5] = (__bf16)b[1]; f[6] = (__bf16)b[2]; f[7] = (__bf16)b[3];
            aQ[ks] = f;
        }
    }

    // =================== Loop 1: QK^T + bias -> e (bf16 regs), lane-local sums ===================
    bf16x4 xsb[NKT][4];                // 64 VGPR: e values for this thread
    float ssum[4] = {0.f, 0.f, 0.f, 0.f};

    #pragma unroll
    for (int kt = 0; kt < NKT; ++kt) {
        const int bufK = (kt & 1) ? SA1 : SA0;
        // write staged K regs -> LDS (vmcnt wait lands here)
        #pragma unroll
        for (int i = 0; i < 8; ++i) {
            bf16x4 b;
            b[0] = (__bf16)kv[i][0]; b[1] = (__bf16)kv[i][1];
            b[2] = (__bf16)kv[i][2]; b[3] = (__bf16)kv[i][3];
            *(bf16x4*)kadr(smem, bufK, srow + 16 * i, sdg * 8) = b;
        }
        __syncthreads();               // K(kt) visible; K(kt-2) readers finished at B(kt-1)

        // issue next K tile loads (in flight across MFMA + exp)
        if (kt < NKT - 1) {
            #pragma unroll
            for (int i = 0; i < 8; ++i)
                kv[i] = *(const f32x4*)(Kh + (size_t)((kt + 1) * KT + srow + 16 * i) * DH + sdg * 4);
        }
        // bias for this tile (hidden under MFMA)
        const int colg = kt * KT + ch * 64 + lm;
        float bb[4][4];
        #pragma unroll
        for (int r = 0; r < 4; ++r) {
            const float* brow = bias + (size_t)(q0 + rowg_l + r) * SEQ + colg;
            bb[r][0] = brow[0]; bb[r][1] = brow[16]; bb[r][2] = brow[32]; bb[r][3] = brow[48];
        }

        f32x4 acc[4] = {{0,0,0,0},{0,0,0,0},{0,0,0,0},{0,0,0,0}};
        __builtin_amdgcn_s_setprio(1);
        #pragma unroll
        for (int ks = 0; ks < 2; ++ks) {
            #pragma unroll
            for (int c = 0; c < 4; ++c) {
                bf16x8 bf = *(const bf16x8*)kadr(smem, bufK, (ch * 4 + c) * 16 + lm, ks * 64 + lq * 16);
                acc[c] = __builtin_amdgcn_mfma_f32_16x16x32_bf16(aQ[ks], bf, acc[c], 0, 0, 0);
            }
        }
        __builtin_amdgcn_s_setprio(0);

        // e = exp(x*scale + bias): f32 sums, bf16 register carrier
        #pragma unroll
        for (int c = 0; c < 4; ++c) {
            #pragma unroll
            for (int r = 0; r < 4; ++r) {
                float e = __expf(acc[c][r] * scale + bb[r][c]);
                ssum[r] += e;
                xsb[kt][c][r] = (__bf16)e;
            }
        }
    }

    // ---- mid: row-sum reduce, V tile-0 prefetch, linv ----
    #pragma unroll
    for (int r = 0; r < 4; ++r) {
        float s = ssum[r];
        #pragma unroll
        for (int off = 1; off < 16; off <<= 1)
            s += __shfl_xor(s, off);
        ssum[r] = s;
    }
    f32x4 vv[2][4];
    #pragma unroll
    for (int i = 0; i < 2; ++i)
        #pragma unroll
        for (int jj = 0; jj < 4; ++jj)
            vv[i][jj] = *(const f32x4*)(Vh + (size_t)(vkb * 4 + jj) * DH + (vdb0 + 8 * i) * 4);

    float* sRLp = (float*)(smem + SRL);
    if (lm == 0) {
        #pragma unroll
        for (int r = 0; r < 4; ++r)
            sRLp[ch * 32 + rowg_l + r] = ssum[r];
    }
    __syncthreads();                   // sRL visible; all loop-1 region-A reads done

    float linv[4], linv_st[4];
    #pragma unroll
    for (int r = 0; r < 4; ++r)
        linv[r] = 1.0f / (sRLp[rowg_l + r] + sRLp[32 + rowg_l + r]);
    #pragma unroll
    for (int j = 0; j < 4; ++j) {
        int row = (w << 3) + 2 * j + (l >> 5);   // this lane's attn-store rows
        linv_st[j] = 1.0f / (sRLp[row] + sRLp[32 + row]);
    }

    // =================== Loop 2: stage sV^T/sP, attn full-sector NT stores, PV ===================
    const int dtb = ch * 2;            // 2 d-subtiles of 16 per wave
    f32x4 oacc[2] = {{0,0,0,0},{0,0,0,0}};

    #pragma unroll
    for (int kt = 0; kt < NKT; ++kt) {
        const int bufV = (kt & 1) ? SA1 : SA0;
        const int bufP = (kt & 1) ? SP1 : SP0;

        // write staged V regs -> sV^T (4x4 micro-transpose; R3's 0-conflict pattern)
        #pragma unroll
        for (int i = 0; i < 2; ++i) {
            int d0 = (vdb0 + 8 * i) * 4;
            #pragma unroll
            for (int jj = 0; jj < 4; ++jj) {
                bf16x4 b;
                b[0] = (__bf16)vv[i][0][jj]; b[1] = (__bf16)vv[i][1][jj];
                b[2] = (__bf16)vv[i][2][jj]; b[3] = (__bf16)vv[i][3][jj];
                *(bf16x4*)vadr(smem, bufV, d0 + jj, vkb * 8) = b;
            }
        }
        // write sP = raw bf16 e (R3's 0-conflict pattern)
        #pragma unroll
        for (int c = 0; c < 4; ++c)
            #pragma unroll
            for (int r = 0; r < 4; ++r)
                *(__bf16*)vadr(smem, bufP, rowg_l + r, ch * 128 + 32 * c + 2 * lm) = xsb[kt][c][r];
        __syncthreads();               // sV(kt)+sP(kt) visible; kt-2 readers done at B(kt-1)

        // issue next V tile (consumed at next iter's top)
        if (kt < NKT - 1) {
            #pragma unroll
            for (int i = 0; i < 2; ++i)
                #pragma unroll
                for (int jj = 0; jj < 4; ++jj)
                    vv[i][jj] = *(const f32x4*)(Vh + (size_t)((kt + 1) * KT + vkb * 4 + jj) * DH + (vdb0 + 8 * i) * 4);
        }

        // attn NT stores from sP readback: each instruction covers 2 rows x 512 B
        // contiguous (full 256 B sectors) -> no NT write amplification.
        #pragma unroll
        for (int j = 0; j < 4; ++j) {
            const int row = (w << 3) + 2 * j + (l >> 5);
            bf16x4 pv = *(const bf16x4*)vadr(smem, bufP, row, (l & 31) * 8);
            f32x4 wv;
            #pragma unroll
            for (int i = 0; i < 4; ++i) wv[i] = (float)pv[i] * linv_st[j];
            __builtin_nontemporal_store(wv,
                (f32x4*)(attnh + (size_t)(q0 + row) * SEQ + kt * KT + (l & 31) * 4));
        }

        // PV on unnormalized e
        __builtin_amdgcn_s_setprio(1);
        #pragma unroll
        for (int ks = 0; ks < 4; ++ks) {
            bf16x8 af = *(const bf16x8*)vadr(smem, bufP, qt * 16 + lm, ks * 64 + lq * 16);
            #pragma unroll
            for (int c = 0; c < 2; ++c) {
                bf16x8 bf = *(const bf16x8*)vadr(smem, bufV, (dtb + c) * 16 + lm, ks * 64 + lq * 16);
                oacc[c] = __builtin_amdgcn_mfma_f32_16x16x32_bf16(af, bf, oacc[c], 0, 0, 0);
            }
        }
        __builtin_amdgcn_s_setprio(0);
    }

    // ---- out: scale unnormalized PV accumulator ----
    #pragma unroll
    for (int c = 0; c < 2; ++c)
        #pragma unroll
        for (int r = 0; r < 4; ++r)
            __builtin_nontemporal_store(oacc[c][r] * linv[r],
                outh + (size_t)(q0 + rowg_l + r) * DH + (dtb + c) * 16 + lm);
}

extern "C" void kernel_launch(void* const* d_in, const int* in_sizes, int n_in,
                              void* d_out, int out_size, void* d_ws, size_t ws_size,
                              hipStream_t stream) {
    const float* Q    = (const float*)d_in[0];
    const float* K    = (const float*)d_in[1];
    const float* V    = (const float*)d_in[2];
    const float* bias = (const float*)d_in[3];
    float* out  = (float*)d_out;
    float* attn = (float*)d_out + 4 * 16 * 1024 * 64;
    dim3 grid(64 * (SEQ / QR));
    dim3 block(256);
    attn_flash_kernel<<<grid, block, 0, stream>>>(Q, K, V, bias, out, attn);
}